// Round 1
// baseline (117.454 us; speedup 1.0000x reference)
//
#include <hip/hip_runtime.h>
#include <stdint.h>

// kNN: B=2, N=2048, D=16, K=16. Output (B,N,K,2) int32: [batch_idx, neighbor_idx].
//
// Correctness strategy: match the numpy f32 reference bit-exactly so distance
// ordering (incl. ties) is identical:
//  - per-dim diff (exact f32 sub), square via __fmul_rn (blocks FMA contraction)
//  - numpy pairwise-sum tree for n=16: r[j]=s[j]+s[j+8]; ((r0+r1)+(r2+r3))+((r4+r5)+(r6+r7))
//  - __fsqrt_rn == correctly-rounded f32 sqrt == np.sqrt
//  - sort key = (dist_bits<<32)|idx : monotone for dist>=0, ties -> lower index
//    (matches stable top_k). Iteration 0 drops the self point (dist==0 exactly).

#define NPTS 2048
#define DIMS 16
#define KK 16
#define THREADS 256
#define PER_THREAD (NPTS / THREADS)  // 8

__global__ __launch_bounds__(THREADS) void knn_kernel(
    const float* __restrict__ points, int* __restrict__ out)
{
    const int q = blockIdx.x;          // global query index in [0, B*N)
    const int b = q >> 11;             // N = 2048
    const int n = q & (NPTS - 1);
    const float* bp = points + (size_t)b * NPTS * DIMS;

    __shared__ uint64_t keys[NPTS];        // 16 KB
    __shared__ float    qs[DIMS];
    __shared__ uint64_t wmin[THREADS / 64];

    const int tid = threadIdx.x;
    if (tid < DIMS) qs[tid] = bp[(size_t)n * DIMS + tid];
    __syncthreads();

    float qp[DIMS];
#pragma unroll
    for (int d = 0; d < DIMS; ++d) qp[d] = qs[d];

    // ---- distance phase: each thread handles 8 candidates ----
#pragma unroll
    for (int i = 0; i < PER_THREAD; ++i) {
        const int c = tid + i * THREADS;
        const float* cp = bp + (size_t)c * DIMS;
        float s[DIMS];
#pragma unroll
        for (int d = 0; d < DIMS; ++d) {
            float df = qp[d] - cp[d];
            s[d] = __fmul_rn(df, df);   // no FMA contraction
        }
        // numpy pairwise_sum for n=16
        float r0 = __fadd_rn(s[0], s[8]);
        float r1 = __fadd_rn(s[1], s[9]);
        float r2 = __fadd_rn(s[2], s[10]);
        float r3 = __fadd_rn(s[3], s[11]);
        float r4 = __fadd_rn(s[4], s[12]);
        float r5 = __fadd_rn(s[5], s[13]);
        float r6 = __fadd_rn(s[6], s[14]);
        float r7 = __fadd_rn(s[7], s[15]);
        float t0 = __fadd_rn(r0, r1);
        float t1 = __fadd_rn(r2, r3);
        float t2 = __fadd_rn(r4, r5);
        float t3 = __fadd_rn(r6, r7);
        float d2 = __fadd_rn(__fadd_rn(t0, t1), __fadd_rn(t2, t3));
        float dist = __fsqrt_rn(d2);    // correctly-rounded, == np.sqrt
        keys[c] = ((uint64_t)__float_as_uint(dist) << 32) | (uint32_t)c;
    }
    __syncthreads();

    // ---- selection phase: K+1 iterative arg-mins; first one is self ----
    for (int iter = 0; iter <= KK; ++iter) {
        uint64_t m = ~0ull;
#pragma unroll
        for (int i = 0; i < PER_THREAD; ++i) {
            uint64_t v = keys[tid + i * THREADS];
            if (v < m) m = v;
        }
        // wave-64 shuffle reduce
#pragma unroll
        for (int off = 32; off > 0; off >>= 1) {
            uint64_t o = (uint64_t)__shfl_down((unsigned long long)m, off, 64);
            if (o < m) m = o;
        }
        if ((tid & 63) == 0) wmin[tid >> 6] = m;
        __syncthreads();
        if (tid == 0) {
            uint64_t mm = wmin[0];
#pragma unroll
            for (int w = 1; w < THREADS / 64; ++w)
                if (wmin[w] < mm) mm = wmin[w];
            const int idx = (int)(uint32_t)(mm & 0xffffffffu);
            keys[idx] = ~0ull;          // exclude winner from later rounds
            if (iter > 0) {
                const size_t o = (((size_t)q * KK) + (size_t)(iter - 1)) * 2;
                out[o]     = b;
                out[o + 1] = idx;
            }
        }
        __syncthreads();
    }
}

extern "C" void kernel_launch(void* const* d_in, const int* in_sizes, int n_in,
                              void* d_out, int out_size, void* d_ws, size_t ws_size,
                              hipStream_t stream) {
    (void)d_ws; (void)ws_size; (void)out_size;
    // setup_inputs order: {'features', 'points'} -> d_in[0]=features (unused),
    // d_in[1]=points. Pick by size to be safe (points = 2*2048*16 = 65536).
    const float* points;
    if (n_in >= 2 && in_sizes[1] == 2 * 2048 * 16) {
        points = (const float*)d_in[1];
    } else if (n_in >= 1 && in_sizes[0] == 2 * 2048 * 16) {
        points = (const float*)d_in[0];
    } else {
        points = (const float*)d_in[n_in - 1];
    }
    int* out = (int*)d_out;
    knn_kernel<<<2 * 2048, THREADS, 0, stream>>>(points, out);
}

// Round 2
// 92.353 us; speedup vs baseline: 1.2718x; 1.2718x over previous
//
#include <hip/hip_runtime.h>
#include <stdint.h>

// kNN: B=2, N=2048, D=16, K=16. Output (B,N,K,2) int32: [batch_idx, neighbor_idx].
//
// Bit-exact vs numpy f32 reference (verified absmax=0 in R1):
//  - per-dim diff, square via __fmul_rn (no FMA contraction)
//  - numpy pairwise-sum tree for n=16: r[j]=s[j]+s[j+8]; ((r0+r1)+(r2+r3))+((r4+r5)+(r6+r7))
//  - __fsqrt_rn == np.sqrt (correctly rounded)
//  - key = (dist_bits<<32)|idx : monotone for dist>=0, ties -> lower index
//    (stable top_k semantics). Round 0 pops the global min (self) = reference's
//    [:, :, 1:] slice.
//
// R2 structure: per-thread register sort of 8 keys -> LDS [rank][thread];
// ONE barrier; wave 0 alone runs 17 head-pop selection rounds (no barriers,
// ~no LDS traffic). Waves 1-3 exit after the barrier.

#define NPTS 2048
#define DIMS 16
#define KK 16
#define THREADS 256
#define PER_THREAD (NPTS / THREADS)     // 8
#define HPL (THREADS / 64)              // heads per lane = 4

__device__ __forceinline__ void ce(uint64_t& a, uint64_t& b) {
    uint64_t lo = (a < b) ? a : b;
    uint64_t hi = (a < b) ? b : a;
    a = lo; b = hi;
}

__global__ __launch_bounds__(THREADS) void knn_kernel(
    const float* __restrict__ points, int* __restrict__ out)
{
    const int q = blockIdx.x;          // global query index in [0, B*N)
    const int b = q >> 11;             // N = 2048
    const int n = q & (NPTS - 1);
    const float* bp = points + (size_t)b * NPTS * DIMS;

    __shared__ uint64_t skeys[PER_THREAD][THREADS];   // [rank][thread], 16 KB
    __shared__ float    qs[DIMS];

    const int tid = threadIdx.x;
    if (tid < DIMS) qs[tid] = bp[(size_t)n * DIMS + tid];
    __syncthreads();

    float qp[DIMS];
#pragma unroll
    for (int d = 0; d < DIMS; ++d) qp[d] = qs[d];

    // ---- distance phase: 8 candidates/thread, keys kept in registers ----
    uint64_t k[PER_THREAD];
#pragma unroll
    for (int i = 0; i < PER_THREAD; ++i) {
        const int c = tid + i * THREADS;
        const float4* cp4 = (const float4*)(bp + (size_t)c * DIMS);
        float s[DIMS];
#pragma unroll
        for (int v = 0; v < 4; ++v) {
            float4 cv = cp4[v];
            float d0 = qp[4 * v + 0] - cv.x;
            float d1 = qp[4 * v + 1] - cv.y;
            float d2_ = qp[4 * v + 2] - cv.z;
            float d3 = qp[4 * v + 3] - cv.w;
            s[4 * v + 0] = __fmul_rn(d0, d0);
            s[4 * v + 1] = __fmul_rn(d1, d1);
            s[4 * v + 2] = __fmul_rn(d2_, d2_);
            s[4 * v + 3] = __fmul_rn(d3, d3);
        }
        // numpy pairwise_sum, n=16
        float r0 = __fadd_rn(s[0], s[8]);
        float r1 = __fadd_rn(s[1], s[9]);
        float r2 = __fadd_rn(s[2], s[10]);
        float r3 = __fadd_rn(s[3], s[11]);
        float r4 = __fadd_rn(s[4], s[12]);
        float r5 = __fadd_rn(s[5], s[13]);
        float r6 = __fadd_rn(s[6], s[14]);
        float r7 = __fadd_rn(s[7], s[15]);
        float t0 = __fadd_rn(r0, r1);
        float t1 = __fadd_rn(r2, r3);
        float t2 = __fadd_rn(r4, r5);
        float t3 = __fadd_rn(r6, r7);
        float d2 = __fadd_rn(__fadd_rn(t0, t1), __fadd_rn(t2, t3));
        float dist = __fsqrt_rn(d2);
        k[i] = ((uint64_t)__float_as_uint(dist) << 32) | (uint32_t)c;
    }

    // ---- per-thread sort of 8 (Batcher odd-even merge, 19 CEs) ----
    ce(k[0], k[1]); ce(k[2], k[3]); ce(k[4], k[5]); ce(k[6], k[7]);
    ce(k[0], k[2]); ce(k[1], k[3]); ce(k[4], k[6]); ce(k[5], k[7]);
    ce(k[1], k[2]); ce(k[5], k[6]);
    ce(k[0], k[4]); ce(k[1], k[5]); ce(k[2], k[6]); ce(k[3], k[7]);
    ce(k[1], k[4]); ce(k[3], k[6]);
    ce(k[2], k[4]); ce(k[3], k[5]);
    ce(k[3], k[4]);

#pragma unroll
    for (int j = 0; j < PER_THREAD; ++j) skeys[j][tid] = k[j];
    __syncthreads();

    // ---- selection: wave 0 only, no barriers ----
    if (tid >= 64) return;
    const int lane = tid;

    uint64_t head[HPL];
    int      pos[HPL];
#pragma unroll
    for (int h = 0; h < HPL; ++h) {
        head[h] = skeys[0][lane + 64 * h];
        pos[h] = 1;
    }

    for (int r = 0; r <= KK; ++r) {
        // local argmin over 4 heads
        uint64_t m = head[0]; int hm = 0;
#pragma unroll
        for (int h = 1; h < HPL; ++h)
            if (head[h] < m) { m = head[h]; hm = h; }
        // wave butterfly min -> all lanes hold global min g
        uint64_t g = m;
#pragma unroll
        for (int off = 1; off < 64; off <<= 1) {
            uint64_t o = (uint64_t)__shfl_xor((unsigned long long)g, off, 64);
            if (o < g) g = o;
        }
        // unique winner lane (keys are unique) pops its head + writes output
        if (m == g) {
            if (r > 0) {
                const int idx = (int)(uint32_t)(g & 0xffffffffu);
                const size_t o = (((size_t)q * KK) + (size_t)(r - 1)) * 2;
                out[o]     = b;
                out[o + 1] = idx;
            }
#pragma unroll
            for (int h = 0; h < HPL; ++h) {
                if (hm == h) {
                    head[h] = (pos[h] < PER_THREAD) ? skeys[pos[h]][lane + 64 * h]
                                                    : ~0ull;
                    pos[h]++;
                }
            }
        }
    }
}

extern "C" void kernel_launch(void* const* d_in, const int* in_sizes, int n_in,
                              void* d_out, int out_size, void* d_ws, size_t ws_size,
                              hipStream_t stream) {
    (void)d_ws; (void)ws_size; (void)out_size;
    // setup_inputs order: {'features', 'points'}; pick points by size (2*2048*16).
    const float* points;
    if (n_in >= 2 && in_sizes[1] == 2 * 2048 * 16) {
        points = (const float*)d_in[1];
    } else if (n_in >= 1 && in_sizes[0] == 2 * 2048 * 16) {
        points = (const float*)d_in[0];
    } else {
        points = (const float*)d_in[n_in - 1];
    }
    int* out = (int*)d_out;
    knn_kernel<<<2 * 2048, THREADS, 0, stream>>>(points, out);
}

// Round 3
// 86.986 us; speedup vs baseline: 1.3503x; 1.0617x over previous
//
#include <hip/hip_runtime.h>
#include <stdint.h>

// kNN: B=2, N=2048, D=16, K=16. Output (B,N,K,2) int32: [batch_idx, neighbor_idx].
//
// Bit-exact vs numpy f32 reference (absmax=0 in R1/R2):
//  - per-dim diff, square via __fmul_rn (no FMA contraction)
//  - numpy pairwise-sum tree n=16: r[j]=s[j]+s[j+8]; ((r0+r1)+(r2+r3))+((r4+r5)+(r6+r7))
//  - __fsqrt_rn == np.sqrt (correctly rounded). sqrt is REQUIRED: ordering by d^2
//    differs from ordering by rounded sqrt on adjacent-ULP ties.
//  - key = (dist_bits<<32)|idx : monotone, ties -> lower index (stable top_k).
//    Pop round 0 = global min = self (reference's [:, :, 1:] slice).
//
// R3 structure: 4 queries per block (one per wave). Each thread reads each
// candidate ONCE from L2 (traffic /4 vs R2), computes 4 dists, stores f32 to
// LDS dist[4][2048] (32 KB, candidate index implicit in position). One barrier.
// Then wave w selects for query w: 32 dists/lane -> u64 keys in REGISTERS,
// 4 sorted runs of 8 (Batcher), 17 pop rounds (local 4-head argmin + wave
// butterfly min + register shift-advance). No LDS key traffic, no barriers,
// all 4 waves active in selection.

#define NPTS 2048
#define DIMS 16
#define KK 16
#define THREADS 256
#define NQ 4
#define CPT (NPTS / THREADS)   // 8 candidates per thread
#define PER_LANE (NPTS / 64)   // 32 keys per lane
#define RUNS 4
#define RLEN 8

__device__ __forceinline__ void ce(uint64_t& a, uint64_t& b) {
    uint64_t lo = (a < b) ? a : b;
    uint64_t hi = (a < b) ? b : a;
    a = lo; b = hi;
}

__global__ __launch_bounds__(THREADS, 4) void knn_kernel(
    const float* __restrict__ points, int* __restrict__ out)
{
    const int qbase = blockIdx.x * NQ;       // 4 queries, never straddles batch
    const int b = qbase >> 11;               // N = 2048
    const float* bp = points + (size_t)b * NPTS * DIMS;

    __shared__ float dist[NQ][NPTS];         // 32 KB

    const int tid = threadIdx.x;

    // ---- queries -> registers (same addrs all threads: L1/L2 broadcast) ----
    float qp[NQ][DIMS];
#pragma unroll
    for (int w = 0; w < NQ; ++w) {
        const int n = (qbase + w) & (NPTS - 1);
        const float4* qp4 = (const float4*)(bp + (size_t)n * DIMS);
#pragma unroll
        for (int v = 0; v < 4; ++v) {
            float4 t = qp4[v];
            qp[w][4 * v + 0] = t.x; qp[w][4 * v + 1] = t.y;
            qp[w][4 * v + 2] = t.z; qp[w][4 * v + 3] = t.w;
        }
    }

    // ---- phase 1: each thread: 8 candidates x 4 queries ----
#pragma unroll 2
    for (int i = 0; i < CPT; ++i) {
        const int c = tid + i * THREADS;     // coalesced across threads
        const float4* cp4 = (const float4*)(bp + (size_t)c * DIMS);
        float cv[DIMS];
#pragma unroll
        for (int v = 0; v < 4; ++v) {
            float4 t = cp4[v];
            cv[4 * v + 0] = t.x; cv[4 * v + 1] = t.y;
            cv[4 * v + 2] = t.z; cv[4 * v + 3] = t.w;
        }
#pragma unroll
        for (int w = 0; w < NQ; ++w) {
            float s[DIMS];
#pragma unroll
            for (int d = 0; d < DIMS; ++d) {
                float df = qp[w][d] - cv[d];
                s[d] = __fmul_rn(df, df);
            }
            float r0 = __fadd_rn(s[0], s[8]);
            float r1 = __fadd_rn(s[1], s[9]);
            float r2 = __fadd_rn(s[2], s[10]);
            float r3 = __fadd_rn(s[3], s[11]);
            float r4 = __fadd_rn(s[4], s[12]);
            float r5 = __fadd_rn(s[5], s[13]);
            float r6 = __fadd_rn(s[6], s[14]);
            float r7 = __fadd_rn(s[7], s[15]);
            float t0 = __fadd_rn(r0, r1);
            float t1 = __fadd_rn(r2, r3);
            float t2 = __fadd_rn(r4, r5);
            float t3 = __fadd_rn(r6, r7);
            float d2 = __fadd_rn(__fadd_rn(t0, t1), __fadd_rn(t2, t3));
            dist[w][c] = __fsqrt_rn(d2);
        }
    }
    __syncthreads();

    // ---- phase 2: wave w selects for query qbase+w ----
    const int w = tid >> 6;
    const int lane = tid & 63;

    // load 32 dists (stride-64: 2 lanes/bank distinct addrs = free), make keys
    uint64_t k[PER_LANE];
#pragma unroll
    for (int j = 0; j < PER_LANE; ++j) {
        const int c = lane + 64 * j;
        k[j] = ((uint64_t)__float_as_uint(dist[w][c]) << 32) | (uint32_t)c;
    }

    // 4 sorted runs of 8 (Batcher odd-even merge, 19 CEs each)
#pragma unroll
    for (int r = 0; r < RUNS; ++r) {
        uint64_t* p = k + r * RLEN;
        ce(p[0], p[1]); ce(p[2], p[3]); ce(p[4], p[5]); ce(p[6], p[7]);
        ce(p[0], p[2]); ce(p[1], p[3]); ce(p[4], p[6]); ce(p[5], p[7]);
        ce(p[1], p[2]); ce(p[5], p[6]);
        ce(p[0], p[4]); ce(p[1], p[5]); ce(p[2], p[6]); ce(p[3], p[7]);
        ce(p[1], p[4]); ce(p[3], p[6]);
        ce(p[2], p[4]); ce(p[3], p[5]);
        ce(p[3], p[4]);
    }

    // ---- 17 pop rounds; round 0 discards self ----
    for (int r = 0; r <= KK; ++r) {
        uint64_t m = k[0]; int hm = 0;
        if (k[8]  < m) { m = k[8];  hm = 1; }
        if (k[16] < m) { m = k[16]; hm = 2; }
        if (k[24] < m) { m = k[24]; hm = 3; }
        uint64_t g = m;
#pragma unroll
        for (int off = 1; off < 64; off <<= 1) {
            uint64_t o = (uint64_t)__shfl_xor((unsigned long long)g, off, 64);
            if (o < g) g = o;
        }
        if (m == g) {                        // unique winner lane (keys unique)
            if (r > 0) {
                int2 val;
                val.x = b;
                val.y = (int)(uint32_t)(g & 0xffffffffu);
                *(int2*)(out + (((size_t)(qbase + w) * KK) + (size_t)(r - 1)) * 2) = val;
            }
#pragma unroll
            for (int h = 0; h < RUNS; ++h) {
                if (hm == h) {
#pragma unroll
                    for (int j = 0; j < RLEN - 1; ++j) k[h * RLEN + j] = k[h * RLEN + j + 1];
                    k[h * RLEN + RLEN - 1] = ~0ull;  // sentinel (never a real key)
                }
            }
        }
    }
}

extern "C" void kernel_launch(void* const* d_in, const int* in_sizes, int n_in,
                              void* d_out, int out_size, void* d_ws, size_t ws_size,
                              hipStream_t stream) {
    (void)d_ws; (void)ws_size; (void)out_size;
    // setup_inputs order: {'features', 'points'}; pick points by size (2*2048*16).
    const float* points;
    if (n_in >= 2 && in_sizes[1] == 2 * 2048 * 16) {
        points = (const float*)d_in[1];
    } else if (n_in >= 1 && in_sizes[0] == 2 * 2048 * 16) {
        points = (const float*)d_in[0];
    } else {
        points = (const float*)d_in[n_in - 1];
    }
    int* out = (int*)d_out;
    knn_kernel<<<(2 * 2048) / NQ, THREADS, 0, stream>>>(points, out);
}